// Round 1
// 220.117 us; speedup vs baseline: 1.0147x; 1.0147x over previous
//
#include <hip/hip_runtime.h>

// LongTermSpectralFlatness: x (32, 3000, 201, 2) fp32 -> flatness (32, 3000, 1) fp32
//
// Math (t >= 1):
//   s[t,f]     = (re^2+im^2) * scale[f] * hamm_sq_sum(25)/16000/10
//   welch[t,f] = mean(s[t-10..t-1, f])                  (cnt = max(min(t,10),1))
//   am[t,f]    = mean(welch[t-30..t-1, f]) + 1e-5
//   gm[t,f]    = exp(mean(log(welch[t-30..t-1,f]+1e-5)))   (the -eps+eps cancels!)
//   flat[t]    = log10(2) * sum_f ( log2(am) - mean(log2(welch+eps)) ),  flat[0] = 0
//
// R8: kernel is HBM-bound (~5.9 TB/s achieved); the remaining lever is BYTES.
// LTILE 60 -> 200 cuts halo amplification (HALO+LTILE)/LTILE from 1.67x to
// 1.2x (257 MB -> 185 MB). Grid (32,15)=480 blocks <= 512 resident capacity
// at launch_bounds(256,2): one block-wave, no tail. To keep code size bounded
// (48 groups would be ~40KB straight-line), the main stream is a real
// `#pragma unroll 1` loop over a 6-group body: fr = m%30 statics repeat with
// period LCM(6-group ring, 3-buffer rotation) = 6 groups, so every register
// ring index stays compile-time (no scratch). Only the LDS part[] index and
// DYN's t are runtime. Prefetch terminal clamp is now a runtime pointer
// compare (pf2 < plast), semantically identical to the old GI+2 < GTOT.
// Keep: no l_ring (evict log recomputed from w_ring bitwise-identically),
// 4-step swizzle-only butterfly {16,8,4,2}, pointer-bump addressing,
// batch-fastest grid (halo source tile same XCD), triple-buffer prefetch
// distance 2 groups.

constexpr int TT = 3000;
constexpr int FF = 201;
constexpr int BB = 32;
constexpr int W1 = 10;
constexpr int W2 = 30;
constexpr int HALO = 40;    // W1 + W2
constexpr int LTILE = 200;  // output frames per tile
constexpr int NT = 15;      // 15 * 200 = 3000
#define EPSV 1e-5f
#define CSCALE (9.935f / 160000.0f)  // hamming_sq_sum(25)/16000/M
#define LOG10_2 0.3010299956639812f

/* Prefetch the group 2 ahead of the one being consumed into buffer PB.
   Terminal groups re-read the last valid base: wasted but in-bounds (L1 hit).
   pf2 always points at the last-loaded group base; target valid iff
   pf2 < plast  <=>  (cur group)+2 <= ngroups-1. */
#define PF_RT(PB)                                                              \
  {                                                                            \
    const float2* pn = (pf2 < plast) ? (pf2 + 5 * FF) : pf2;                   \
    _Pragma("unroll") for (int j = 0; j < 5; ++j) PB[j] = pn[j * FF];          \
    pf2 = pn;                                                                  \
  }

/* Warm-up A: squares only, fill s_ring (stream groups 0..1, non-first tiles) */
#define WARMA_GROUP(GI, CB, PB)                                                \
  {                                                                            \
    PF_RT(PB);                                                                 \
    _Pragma("unroll") for (int j = 0; j < 5; ++j) {                            \
      float sv = fmaf(CB[j].x, CB[j].x, CB[j].y * CB[j].y) * cs;               \
      ssum += sv;                                                              \
      s_ring[(GI) * 5 + j] = sv;                                               \
    }                                                                          \
  }

/* Warm-up B: welch/log window fill, no eviction (stream groups 2..7).
   welch uses full 10-window always here (t0 >= 200 -> warm frames >= 160). */
#define WARMB_GROUP(GI, CB, PB)                                                \
  {                                                                            \
    PF_RT(PB);                                                                 \
    _Pragma("unroll") for (int j = 0; j < 5; ++j) {                            \
      const int fr = ((GI) - 2) * 5 + j;                                       \
      float welch = ssum * 0.1f;                                               \
      float lw = __log2f(welch + EPSV);                                        \
      wsum += welch; w_ring[fr] = welch;                                       \
      lsum += lw;                                                              \
      float sv = fmaf(CB[j].x, CB[j].x, CB[j].y * CB[j].y) * cs;               \
      ssum += sv - s_ring[fr % 10];                                            \
      s_ring[fr % 10] = sv;                                                    \
    }                                                                          \
  }

/* Main: 5 output frames. U = group phase within the 30-frame period (0..5),
   compile-time, so all register-ring indices are static. mb = runtime frame
   offset of the period start within the tile (mb % 30 == 0 always).
   DYN: dynamic window counts + no lsum eviction (tile 0, t < 30).
   Non-DYN eviction recomputes the evicted log from w_ring: bitwise equal
   to the lw pushed 30 frames earlier. */
#define MAIN_GROUP_U(U, CB, PB, DYN)                                           \
  {                                                                            \
    PF_RT(PB);                                                                 \
    float rr[5];                                                               \
    _Pragma("unroll") for (int j = 0; j < 5; ++j) {                            \
      const int fr = (U) * 5 + j;                                              \
      float inv10, inv30;                                                      \
      if (DYN) {                                                               \
        const int t = t0 + mb + fr;                                            \
        inv10 = 1.0f / (float)max(min(t, W1), 1);                              \
        inv30 = 1.0f / (float)max(min(t, W2), 1);                              \
      } else {                                                                 \
        inv10 = 0.1f;                                                          \
        inv30 = (1.0f / 30.0f);                                                \
      }                                                                        \
      float welch = ssum * inv10;                                              \
      float lw = __log2f(welch + EPSV);                                        \
      float am = fmaf(wsum, inv30, EPSV);                                      \
      float la = __log2f(am);                                                  \
      rr[j] = (la - lsum * inv30) * LOG10_2;                                   \
      float wold = w_ring[fr];                                                 \
      if (DYN) lsum += lw;                                                     \
      else     lsum += lw - __log2f(wold + EPSV);                              \
      wsum += welch - wold;                                                    \
      w_ring[fr] = welch;                                                      \
      float sv = fmaf(CB[j].x, CB[j].x, CB[j].y * CB[j].y) * cs;               \
      ssum += sv - s_ring[fr % 10];                                            \
      s_ring[fr % 10] = sv;                                                    \
    }                                                                          \
    /* 4-step butterfly, swizzle-only masks; partials in lanes 0,1,32,33 */    \
    _Pragma("unroll") for (int off = 16; off >= 2; off >>= 1) {                \
      _Pragma("unroll") for (int j = 0; j < 5; ++j)                            \
          rr[j] += __shfl_xor(rr[j], off, 64);                                 \
    }                                                                          \
    if ((lane & 30) == 0) {                                                    \
      const int p = (lane & 1) | ((lane >> 4) & 2);                            \
      _Pragma("unroll") for (int j = 0; j < 5; ++j)                            \
          ((float*)&part[wv][mb + (U) * 5 + j])[p] = rr[j];                    \
    }                                                                          \
  }

__global__ __launch_bounds__(256, 2)
void ltsf_kernel(const float2* __restrict__ x, float* __restrict__ out) {
  const int tid = threadIdx.x;
  const int b = blockIdx.x;     // batch fastest: tile & tile-1 same XCD (%8)
  const int tile = blockIdx.y;
  const int t0 = tile * LTILE;
  const bool first = (tile == 0);
  const int tstart = first ? 0 : (t0 - HALO);
  const int ngroups = first ? (LTILE / 5) : ((LTILE + HALO) / 5);  // 40 / 48
  const int lane = tid & 63;
  const int wv = tid >> 6;

  // freq bin; lanes >= 201 are zero-scale (their contrib is exactly 0 for t>=1)
  const int f = (tid < FF) ? tid : (FF - 1);
  float cs = (tid < FF) ? ((tid == 0 || tid == FF - 1) ? 1.0f : 2.0f) : 0.0f;
  cs *= CSCALE;

  const float2* xb = x + (size_t)b * TT * FF;

  __shared__ float4 part[4][LTILE];

  float s_ring[W1], w_ring[W2];
#pragma unroll
  for (int j = 0; j < W1; ++j) s_ring[j] = 0.f;
#pragma unroll
  for (int j = 0; j < W2; ++j) w_ring[j] = 0.f;
  float ssum = 0.f, wsum = 0.f, lsum = 0.f;

  float2 bufA[5], bufB[5], bufC[5];

  // preload stream groups 0 and 1; pf2 tracks the last-loaded group base
  const float2* p0 = xb + (size_t)tstart * FF + f;
  const float2* const plast = p0 + (size_t)(ngroups - 1) * 5 * FF;
#pragma unroll
  for (int j = 0; j < 5; ++j) bufA[j] = p0[j * FF];
  const float2* pf2 = p0 + 5 * FF;
#pragma unroll
  for (int j = 0; j < 5; ++j) bufB[j] = pf2[j * FF];

  if (!first) {
    // stream: 2 warm-A + 6 warm-B + 40 main = 48 groups (frames t0-40..t0+199)
    // group g uses buffer g%3, prefetches into (g+2)%3
    WARMA_GROUP(0, bufA, bufC)
    WARMA_GROUP(1, bufB, bufA)
    WARMB_GROUP(2, bufC, bufB)
    WARMB_GROUP(3, bufA, bufC)
    WARMB_GROUP(4, bufB, bufA)
    WARMB_GROUP(5, bufC, bufB)
    WARMB_GROUP(6, bufA, bufC)
    WARMB_GROUP(7, bufB, bufA)
    // main groups start at g=8 (g%3==2 -> bufC); 6 iters x 6 groups + 4 rem
    int mb = 0;
#pragma unroll 1
    for (int i = 0; i < 6; ++i) {
      MAIN_GROUP_U(0, bufC, bufB, false)
      MAIN_GROUP_U(1, bufA, bufC, false)
      MAIN_GROUP_U(2, bufB, bufA, false)
      MAIN_GROUP_U(3, bufC, bufB, false)
      MAIN_GROUP_U(4, bufA, bufC, false)
      MAIN_GROUP_U(5, bufB, bufA, false)
      mb += 30;
    }
    /* remainder: groups 44..47, mb == 180, frames t0+180..t0+199 */
    MAIN_GROUP_U(0, bufC, bufB, false)
    MAIN_GROUP_U(1, bufA, bufC, false)
    MAIN_GROUP_U(2, bufB, bufA, false)
    MAIN_GROUP_U(3, bufC, bufB, false)
  } else {
    // tile 0: 40 main groups (frames 0..199); t<30 dynamic, no eviction
    // group g uses buffer g%3, prefetches into (g+2)%3
    int mb = 0;
    MAIN_GROUP_U(0, bufA, bufC, true)
    MAIN_GROUP_U(1, bufB, bufA, true)
    MAIN_GROUP_U(2, bufC, bufB, true)
    MAIN_GROUP_U(3, bufA, bufC, true)
    MAIN_GROUP_U(4, bufB, bufA, true)
    MAIN_GROUP_U(5, bufC, bufB, true)
    // main loop from g=6 (g%3==0 -> bufA); 5 iters x 6 groups + 4 rem
    mb = 30;
#pragma unroll 1
    for (int i = 0; i < 5; ++i) {
      MAIN_GROUP_U(0, bufA, bufC, false)
      MAIN_GROUP_U(1, bufB, bufA, false)
      MAIN_GROUP_U(2, bufC, bufB, false)
      MAIN_GROUP_U(3, bufA, bufC, false)
      MAIN_GROUP_U(4, bufB, bufA, false)
      MAIN_GROUP_U(5, bufC, bufB, false)
      mb += 30;
    }
    /* remainder: groups 36..39, mb == 180, frames 180..199 */
    MAIN_GROUP_U(0, bufA, bufC, false)
    MAIN_GROUP_U(1, bufB, bufA, false)
    MAIN_GROUP_U(2, bufC, bufB, false)
    MAIN_GROUP_U(3, bufA, bufC, false)
  }

  // ---- epilogue: sum the 16 partials (4 waves x 4 lanes) per frame ----
  __syncthreads();
  if (tid < LTILE) {
    float4 v0 = part[0][tid], v1 = part[1][tid];
    float4 v2 = part[2][tid], v3 = part[3][tid];
    float v = ((v0.x + v0.y) + (v0.z + v0.w)) + ((v1.x + v1.y) + (v1.z + v1.w)) +
              ((v2.x + v2.y) + (v2.z + v2.w)) + ((v3.x + v3.y) + (v3.z + v3.w));
    if (first && tid == 0) v = 0.f;  // reference forces frame 0 to exactly 0
    out[(size_t)b * TT + t0 + tid] = v;
  }
}

extern "C" void kernel_launch(void* const* d_in, const int* in_sizes, int n_in,
                              void* d_out, int out_size, void* d_ws, size_t ws_size,
                              hipStream_t stream) {
  const float2* x = (const float2*)d_in[0];
  float* out = (float*)d_out;
  dim3 grid(BB, NT);  // batch fastest: halo source tile lands on same XCD
  ltsf_kernel<<<grid, 256, 0, stream>>>(x, out);
}